// Round 2
// baseline (251.611 us; speedup 1.0000x reference)
//
#include <hip/hip_runtime.h>

// GNN: 2x GCNConv(relu) + mean-pool + MLP head.
// Sizes fixed: N=50000, E=800000, F_IN=256, H=64, NG=64, NC=4.
//
// R9: hs/hb bf16, f32 accumulate. R10: deep gather pipeline.
// R11: dual-edge packed gather (2 edges per VMEM instr).
// R13: GEMMs moved from VALU f32-FMA to bf16 MFMA (16x16x32). f32 input
// handled by split-bf16 (hi+lo), 3 MFMA products -> f32-class accuracy.
// LDS tiles XOR-swizzled (T2-style, 16B granule) for conflict-free
// ds_read_b128 fragments. 48KB LDS.
// R14: resubmit of R13 — round 1 failed on container infra, no kernel
// signal; code audit found no fault/hang vector.

#define TPB 256
#define CHUNK_A 4096
#define BCAP 4608          // per-bucket staging capacity (mean 4096, +8 sigma)

typedef unsigned short bfu;
typedef __attribute__((ext_vector_type(8))) short s16x8;
typedef __attribute__((ext_vector_type(4))) float f32x4;

__device__ __forceinline__ float bf2f(bfu u) {
    union { unsigned u32; float f; } c; c.u32 = ((unsigned)u) << 16; return c.f;
}
__device__ __forceinline__ bfu f2bf(float f) {
    union { float f; unsigned u; } c; c.f = f;
    unsigned r = 0x7FFFu + ((c.u >> 16) & 1u);     // round-to-nearest-even
    return (bfu)((c.u + r) >> 16);
}
__device__ __forceinline__ float blo(unsigned w) {
    union { unsigned u32; float f; } c; c.u32 = w << 16; return c.f;
}
__device__ __forceinline__ float bhi(unsigned w) {
    union { unsigned u32; float f; } c; c.u32 = w & 0xFFFF0000u; return c.f;
}
__device__ __forceinline__ void split_bf(float x, bfu& h, bfu& l) {
    h = f2bf(x);
    l = f2bf(x - bf2f(h));
}

// ---------------- pass A: chunked bucket staging ----------------
// packed edge: (src<<8) | (dst & 255); requires n <= 65536, nbuck <= 256.

__global__ __launch_bounds__(TPB) void k_passA(const int* __restrict__ srcv,
                                               const int* __restrict__ dstv, int E,
                                               int* __restrict__ gcur,
                                               int* __restrict__ staged, int nbuck) {
    __shared__ int pk[CHUNK_A];
    __shared__ int hist[256];
    __shared__ int ebase[256];
    __shared__ int gbase[256];
    __shared__ int lcur[256];
    int t = threadIdx.x;
    int e0 = blockIdx.x * CHUNK_A;
    int e1 = e0 + CHUNK_A; if (e1 > E) e1 = E;

    hist[t] = 0; lcur[t] = 0;
    __syncthreads();
    for (int i = e0 + t; i < e1; i += TPB) atomicAdd(&hist[dstv[i] >> 8], 1);
    __syncthreads();
    int v = hist[t];
    ebase[t] = v;
    __syncthreads();
    for (int off = 1; off < 256; off <<= 1) {
        int u = (t >= off) ? ebase[t - off] : 0;
        __syncthreads();
        ebase[t] += u;
        __syncthreads();
    }
    ebase[t] -= v;
    if (t < nbuck && v > 0) gbase[t] = t * BCAP + atomicAdd(&gcur[t], v);
    __syncthreads();
    for (int i = e0 + t; i < e1; i += TPB) {
        int d = dstv[i];
        int s = srcv[i];
        int b = d >> 8;
        int r = atomicAdd(&lcur[b], 1);
        pk[ebase[b] + r] = (s << 8) | (d & 255);
    }
    __syncthreads();
    int wave = t >> 6, lane = t & 63;
    for (int b = wave; b < nbuck; b += 4) {
        int c = hist[b];
        int lb = ebase[b];
        int gb = gbase[b];
        for (int j = lane; j < c; j += 64) staged[gb + j] = pk[lb + j];
    }
}

// ---------------- pass B: per-bucket node sort + csr_off + dinv ----------------

__global__ __launch_bounds__(TPB) void k_passB(const int* __restrict__ staged,
                                               const int* __restrict__ gcur,
                                               int* __restrict__ csr_off,
                                               int* __restrict__ csr_src,
                                               float* __restrict__ dinv,
                                               int n, int nbuck) {
    __shared__ int pk[BCAP];
    __shared__ int soff[256];
    __shared__ int hist[256];
    __shared__ int nbase[256];
    __shared__ int cur[256];
    int b = blockIdx.x;
    int n0 = b << 8;
    int n1 = n0 + 256; if (n1 > n) n1 = n;
    int cnt = gcur[b];
    int t = threadIdx.x;

    int cv = (t < nbuck) ? gcur[t] : 0;
    soff[t] = cv;
    hist[t] = 0; cur[t] = 0;
    __syncthreads();
    for (int off = 1; off < 256; off <<= 1) {
        int u = (t >= off) ? soff[t - off] : 0;
        __syncthreads();
        soff[t] += u;
        __syncthreads();
    }
    int base = soff[b] - cnt;   // exclusive prefix at bucket b

    for (int i = t; i < cnt; i += TPB) pk[i] = staged[b * BCAP + i];
    __syncthreads();
    for (int i = t; i < cnt; i += TPB) atomicAdd(&hist[pk[i] & 255], 1);
    __syncthreads();
    int v = hist[t];
    nbase[t] = v;
    __syncthreads();
    for (int off = 1; off < 256; off <<= 1) {
        int u = (t >= off) ? nbase[t - off] : 0;
        __syncthreads();
        nbase[t] += u;
        __syncthreads();
    }
    nbase[t] -= v;
    if (n0 + t < n1) {
        csr_off[n0 + t] = base + nbase[t];
        dinv[n0 + t] = rsqrtf((float)(v + 1));   // +1 self loop
    }
    if (b == nbuck - 1 && t == 0) csr_off[n] = base + cnt;
    __syncthreads();
    for (int i = t; i < cnt; i += TPB) {
        int p = pk[i];
        int dloc = p & 255;
        int r = atomicAdd(&cur[dloc], 1);
        csr_src[base + nbase[dloc] + r] = p >> 8;
    }
}

// ---------------- GEMM (MFMA): C[r][j] = dinv[r] * sum_k A[r][k] * W[k][j] ----------------
// Block = 128 rows x 64 cols, 4 waves; wave = 32 rows x 64 cols
// (2 row-tiles x 4 col-tiles of 16x16, K-step 32). K-chunk 64 in LDS.
// f32 A: split-bf16 hi/lo planes, products hi*hi + hi*lo + lo*hi.
// bf16 A: single plane, W split hi/lo (2 products) to keep f32-class W.
// LDS XOR swizzle: element k ^ ((row&7)<<3) -> 16B-granule permutation
// within the 128B row; frag ds_read_b128 <=2-way bank conflict.
// Layout safety: A and B fragments use the identical (lane>>4)*8+j -> k
// map, so any HW within-k-step permutation cancels; C/D map is the
// m89-verified col=lane&15, row=(lane>>4)*4+reg.

__device__ __forceinline__ int swz(int rc, int k) {
    return rc * 64 + (k ^ ((rc & 7) << 3));
}

template <int K, bool BF16A>
__global__ __launch_bounds__(TPB) void k_gemm(const void* __restrict__ Av,
                                              const float* __restrict__ W,
                                              const float* __restrict__ dinv,
                                              bfu* __restrict__ C, int n) {
    __shared__ __align__(16) ushort Ah[128 * 64];
    __shared__ __align__(16) ushort Al[BF16A ? 64 : 128 * 64];
    __shared__ __align__(16) ushort Bh[64 * 64];
    __shared__ __align__(16) ushort Bl[64 * 64];

    const int t = threadIdx.x;
    const int wave = t >> 6, lane = t & 63;
    const int rbase = blockIdx.x * 128;

    f32x4 acc[2][4];
#pragma unroll
    for (int i = 0; i < 2; i++)
#pragma unroll
        for (int j = 0; j < 4; j++) acc[i][j] = {0.f, 0.f, 0.f, 0.f};

    for (int kc = 0; kc < K; kc += 64) {
        // ---- stage B: W chunk [64k x 64c] -> transposed bf16 hi/lo ----
        {
            int c = t & 63;
            int kg = (t >> 6) << 4;   // 16 k's per wave
#pragma unroll
            for (int q = 0; q < 4; q++) {
                ushort4 h4, l4;
#pragma unroll
                for (int j = 0; j < 4; j++) {
                    float w = W[(size_t)(kc + kg + q * 4 + j) * 64 + c];
                    bfu hh, ll; split_bf(w, hh, ll);
                    ((bfu*)&h4)[j] = hh;
                    ((bfu*)&l4)[j] = ll;
                }
                *(ushort4*)&Bh[swz(c, kg + q * 4)] = h4;
                *(ushort4*)&Bl[swz(c, kg + q * 4)] = l4;
            }
        }
        // ---- stage A chunk [128r x 64k] ----
        if (!BF16A) {
            const float* A = (const float*)Av;
#pragma unroll
            for (int q = 0; q < 8; q++) {
                int idx = q * 256 + t;
                int row = idx >> 4;
                int k4 = (idx & 15) << 2;
                int r = rbase + row;
                float4 xv = make_float4(0.f, 0.f, 0.f, 0.f);
                if (r < n) xv = *(const float4*)&A[(size_t)r * K + kc + k4];
                ushort4 h4, l4;
                split_bf(xv.x, ((bfu*)&h4)[0], ((bfu*)&l4)[0]);
                split_bf(xv.y, ((bfu*)&h4)[1], ((bfu*)&l4)[1]);
                split_bf(xv.z, ((bfu*)&h4)[2], ((bfu*)&l4)[2]);
                split_bf(xv.w, ((bfu*)&h4)[3], ((bfu*)&l4)[3]);
                *(ushort4*)&Ah[swz(row, k4)] = h4;
                *(ushort4*)&Al[swz(row, k4)] = l4;
            }
        } else {
            const bfu* A = (const bfu*)Av;
#pragma unroll
            for (int q = 0; q < 4; q++) {
                int idx = q * 256 + t;
                int row = idx >> 3;
                int k8 = (idx & 7) << 3;
                int r = rbase + row;
                uint4 v = make_uint4(0u, 0u, 0u, 0u);
                if (r < n) v = *(const uint4*)(A + (size_t)r * 64 + k8);
                *(uint2*)&Ah[swz(row, k8)]     = make_uint2(v.x, v.y);
                *(uint2*)&Ah[swz(row, k8 + 4)] = make_uint2(v.z, v.w);
            }
        }
        __syncthreads();

        // ---- MFMA compute ----
        const int rl = lane & 15;            // M/N index within tile
        const int kg8 = (lane >> 4) << 3;    // k offset of this lane group
#pragma unroll
        for (int ks = 0; ks < 2; ks++) {
            int k0 = ks * 32 + kg8;
            s16x8 a_h[2], a_l[2], b_h[4], b_l[4];
#pragma unroll
            for (int rt = 0; rt < 2; rt++) {
                int row = wave * 32 + rt * 16 + rl;
                a_h[rt] = *(const s16x8*)&Ah[swz(row, k0)];
                if (!BF16A) a_l[rt] = *(const s16x8*)&Al[swz(row, k0)];
            }
#pragma unroll
            for (int ct = 0; ct < 4; ct++) {
                int cc = ct * 16 + rl;
                b_h[ct] = *(const s16x8*)&Bh[swz(cc, k0)];
                b_l[ct] = *(const s16x8*)&Bl[swz(cc, k0)];
            }
#pragma unroll
            for (int rt = 0; rt < 2; rt++)
#pragma unroll
                for (int ct = 0; ct < 4; ct++) {
                    acc[rt][ct] = __builtin_amdgcn_mfma_f32_16x16x32_bf16(
                        a_h[rt], b_h[ct], acc[rt][ct], 0, 0, 0);
                    acc[rt][ct] = __builtin_amdgcn_mfma_f32_16x16x32_bf16(
                        a_h[rt], b_l[ct], acc[rt][ct], 0, 0, 0);
                    if (!BF16A)
                        acc[rt][ct] = __builtin_amdgcn_mfma_f32_16x16x32_bf16(
                            a_l[rt], b_h[ct], acc[rt][ct], 0, 0, 0);
                }
        }
        __syncthreads();
    }

    // ---- epilogue: D[row][col]: col = lane&15, row = (lane>>4)*4 + reg ----
    const int rl = lane & 15;
    const int rq = (lane >> 4) << 2;
#pragma unroll
    for (int rt = 0; rt < 2; rt++) {
#pragma unroll
        for (int reg = 0; reg < 4; reg++) {
            int r = rbase + wave * 32 + rt * 16 + rq + reg;
            if (r < n) {
                float d = dinv[r];
#pragma unroll
                for (int ct = 0; ct < 4; ct++) {
                    C[(size_t)r * 64 + ct * 16 + rl] = f2bf(acc[rt][ct][reg] * d);
                }
            }
        }
    }
}

// ---------------- Aggregation: dual-edge packed gather (R11) ----------------
// Wave = 2 halves of 32 lanes; lane handles 2 features (uint = 2 bf16).
// One gather instruction covers 2 edges (256B). Halves combined by shfl_xor.

__global__ __launch_bounds__(TPB) void k_agg(const bfu* __restrict__ hs,
                                             const int* __restrict__ csr_off,
                                             const int* __restrict__ csr_src,
                                             const float* __restrict__ dinv,
                                             const float* __restrict__ bias,
                                             bfu* __restrict__ out, int n) {
    int node = blockIdx.x * 4 + (threadIdx.x >> 6);
    int lane = threadIdx.x & 63;
    int half = lane >> 5;          // 0 or 1
    int fl = (lane & 31) * 2;      // feature pair base
    if (node >= n) return;
    int p0 = csr_off[node];
    int p1 = csr_off[node + 1];

    float ax = 0.f, ay = 0.f;
    {   // self loop: half 0 only
        unsigned g = *(const unsigned*)(hs + (size_t)node * 64 + fl);
        if (half == 0) { ax = blo(g); ay = bhi(g); }
    }
    int p = p0;
    // 8 edge-pairs = 16 edges in flight
    for (; p + 16 <= p1; p += 16) {
        int s[8]; unsigned g[8];
#pragma unroll
        for (int i = 0; i < 8; i++) s[i] = csr_src[p + 2 * i + half];
#pragma unroll
        for (int i = 0; i < 8; i++) g[i] = *(const unsigned*)(hs + (size_t)s[i] * 64 + fl);
#pragma unroll
        for (int i = 0; i < 8; i++) { ax += blo(g[i]); ay += bhi(g[i]); }
    }
    if (p + 8 <= p1) {
        int s[4]; unsigned g[4];
#pragma unroll
        for (int i = 0; i < 4; i++) s[i] = csr_src[p + 2 * i + half];
#pragma unroll
        for (int i = 0; i < 4; i++) g[i] = *(const unsigned*)(hs + (size_t)s[i] * 64 + fl);
#pragma unroll
        for (int i = 0; i < 4; i++) { ax += blo(g[i]); ay += bhi(g[i]); }
        p += 8;
    }
    if (p + 4 <= p1) {
        int s[2]; unsigned g[2];
#pragma unroll
        for (int i = 0; i < 2; i++) s[i] = csr_src[p + 2 * i + half];
#pragma unroll
        for (int i = 0; i < 2; i++) g[i] = *(const unsigned*)(hs + (size_t)s[i] * 64 + fl);
#pragma unroll
        for (int i = 0; i < 2; i++) { ax += blo(g[i]); ay += bhi(g[i]); }
        p += 4;
    }
    if (p + 2 <= p1) {
        int s = csr_src[p + half];
        unsigned g = *(const unsigned*)(hs + (size_t)s * 64 + fl);
        ax += blo(g); ay += bhi(g);
        p += 2;
    }
    if (p < p1) {   // odd tail: half 0 only
        int s = csr_src[p];
        unsigned g = *(const unsigned*)(hs + (size_t)s * 64 + fl);
        if (half == 0) { ax += blo(g); ay += bhi(g); }
    }
    // combine halves (same fl in lane and lane^32)
    ax += __shfl_xor(ax, 32);
    ay += __shfl_xor(ay, 32);

    float d = dinv[node];
    float vx = fmaxf(d * ax + bias[fl + 0], 0.f);
    float vy = fmaxf(d * ay + bias[fl + 1], 0.f);
    if (half == 0) {
        ushort2 o;
        o.x = f2bf(vx);
        o.y = f2bf(vy);
        *(ushort2*)(out + (size_t)node * 64 + fl) = o;
    }
}

// ---------------- Pool: sorted batch; uniform-chunk fast path (bf16 reads) ----------------

__global__ __launch_bounds__(TPB) void k_pool(const bfu* __restrict__ h,
                                              const int* __restrict__ batch, int n,
                                              float* __restrict__ gsum,
                                              int* __restrict__ gcnt) {
    const int CH = 16;
    int wid = blockIdx.x * 4 + (threadIdx.x >> 6);
    int lane = threadIdx.x & 63;
    int i0 = wid * CH;
    if (i0 >= n) return;
    int i1 = i0 + CH; if (i1 > n) i1 = n;
    int g0 = batch[i0];
    int g1 = batch[i1 - 1];
    if (g0 == g1) {
        float acc = 0.f;
#pragma unroll
        for (int i = 0; i < CH; i++) {
            int idx = i0 + i;
            if (idx < i1) acc += bf2f(h[(size_t)idx * 64 + lane]);
        }
        atomicAdd(&gsum[g0 * 64 + lane], acc);
        if (lane == 0) atomicAdd(&gcnt[g0], i1 - i0);
    } else {
        int cur = g0;
        float acc = 0.f;
        int cnt = 0;
        for (int i = i0; i < i1; i++) {
            int g = batch[i];
            if (g != cur) {
                atomicAdd(&gsum[cur * 64 + lane], acc);
                if (lane == 0) atomicAdd(&gcnt[cur], cnt);
                acc = 0.f; cnt = 0; cur = g;
            }
            acc += bf2f(h[(size_t)i * 64 + lane]);
            cnt++;
        }
        atomicAdd(&gsum[cur * 64 + lane], acc);
        if (lane == 0) atomicAdd(&gcnt[cur], cnt);
    }
}

// ---------------- Head, stage 1 ----------------

__global__ __launch_bounds__(TPB) void k_head1(const float* __restrict__ gsum,
                                               const int* __restrict__ gcnt,
                                               const float* __restrict__ fc1w,
                                               const float* __restrict__ fc1b,
                                               float* __restrict__ z) {
    int t = threadIdx.x;
    int g = blockIdx.x * 2 + (t >> 7);
    int o = t & 127;
    int c = gcnt[g]; if (c < 1) c = 1;
    float inv = 1.0f / (float)c;
    float a = fc1b[o];
#pragma unroll 16
    for (int j = 0; j < 64; j++) {
        float pj = gsum[g * 64 + j] * inv;
        a += pj * fc1w[j * 128 + o];
    }
    z[g * 128 + o] = fmaxf(a, 0.f);
}

// ---------------- Head, stage 2 ----------------

__global__ __launch_bounds__(TPB) void k_head2(const float* __restrict__ z,
                                               const float* __restrict__ fc2w,
                                               const float* __restrict__ fc2b,
                                               float* __restrict__ out) {
    int t = threadIdx.x;
    int g = t >> 2, c = t & 3;
    float a = fc2b[c];
#pragma unroll 16
    for (int o = 0; o < 128; o++) a += z[g * 128 + o] * fc2w[o * 4 + c];
    out[t] = a;
}

// ---------------- launch ----------------

extern "C" void kernel_launch(void* const* d_in, const int* in_sizes, int n_in,
                              void* d_out, int out_size, void* d_ws, size_t ws_size,
                              hipStream_t stream) {
    const float* x    = (const float*)d_in[0];
    const int*   ei   = (const int*)d_in[1];
    const int*   batch= (const int*)d_in[2];
    const float* W1   = (const float*)d_in[3];
    const float* b1   = (const float*)d_in[4];
    const float* W2   = (const float*)d_in[5];
    const float* b2   = (const float*)d_in[6];
    const float* fc1w = (const float*)d_in[7];
    const float* fc1b = (const float*)d_in[8];
    const float* fc2w = (const float*)d_in[9];
    const float* fc2b = (const float*)d_in[10];

    const int n = in_sizes[2];        // 50000
    const int E = in_sizes[1] / 2;    // 800000
    const int* srcv = ei;
    const int* dstv = ei + E;
    const int nbuck = (n + 255) >> 8; // 196 (must be <= 256)

    // workspace carve; zeroed region contiguous at front
    char* w = (char*)d_ws;
    int*   gcur   = (int*)w;            w += 256 * 4;
    int*   gcnt   = (int*)w;            w += 64 * 4;
    float* gsum   = (float*)w;          w += 64 * 64 * 4;
    size_t zbytes = (size_t)w - (size_t)d_ws;
    int*   csr_off= (int*)w;            w += (size_t)(n + 1) * 4;
    float* dinv   = (float*)w;          w += (size_t)n * 4;
    int*   csr_src= (int*)w;            w += (size_t)E * 4;
    int*   staged = (int*)w;            w += (size_t)nbuck * BCAP * 4;
    float* zbuf   = (float*)w;          w += 64 * 128 * 4;
    w = (char*)(((size_t)w + 255) & ~(size_t)255);
    bfu* hs = (bfu*)w;                  w += (size_t)n * 64 * 2;
    w = (char*)(((size_t)w + 255) & ~(size_t)255);
    bfu* hb = (bfu*)w;                  w += (size_t)n * 64 * 2;

    hipMemsetAsync(d_ws, 0, zbytes, stream);

    int gA = (E + CHUNK_A - 1) / CHUNK_A;   // 196
    k_passA<<<gA, TPB, 0, stream>>>(srcv, dstv, E, gcur, staged, nbuck);
    k_passB<<<nbuck, TPB, 0, stream>>>(staged, gcur, csr_off, csr_src, dinv, n, nbuck);

    int gRows = (n + 127) / 128;
    int gNode = (n + 3) / 4;
    k_gemm<256, false><<<gRows, TPB, 0, stream>>>(x, W1, dinv, hs, n);
    k_agg<<<gNode, TPB, 0, stream>>>(hs, csr_off, csr_src, dinv, b1, hb, n);
    k_gemm<64, true><<<gRows, TPB, 0, stream>>>(hb, W2, dinv, hs, n);
    k_agg<<<gNode, TPB, 0, stream>>>(hs, csr_off, csr_src, dinv, b2, hb, n);

    int nwaves16 = (n + 15) / 16;
    k_pool<<<(nwaves16 + 3) / 4, TPB, 0, stream>>>(hb, batch, n, gsum, gcnt);
    k_head1<<<32, TPB, 0, stream>>>(gsum, gcnt, fc1w, fc1b, zbuf);
    k_head2<<<1, TPB, 0, stream>>>(zbuf, fc2w, fc2b, (float*)d_out);
}